// Round 20
// baseline (810.391 us; speedup 1.0000x reference)
//
#include <hip/hip_runtime.h>

typedef unsigned short u16;
typedef unsigned long long u64;
typedef unsigned u32x4_t __attribute__((ext_vector_type(4)));
typedef _Float16 f16x8_t __attribute__((ext_vector_type(8)));
typedef short    i16x8_t __attribute__((ext_vector_type(8)));
typedef float    f32x4_t __attribute__((ext_vector_type(4)));

// force a loaded value to stay materialized in VGPRs (no remat/sinking)
#define PIN(x) asm volatile("" : "+v"(x))

// ---- helpers ---------------------------------------------------------------
static __device__ __forceinline__ u16 f2h(float f) {
  _Float16 h = (_Float16)f;  // RNE
  return __builtin_bit_cast(u16, h);
}
static __device__ __forceinline__ f32x4_t mfma16h(i16x8_t a, i16x8_t b, f32x4_t c) {
  return __builtin_amdgcn_mfma_f32_16x16x32_f16(
      __builtin_bit_cast(f16x8_t, a), __builtin_bit_cast(f16x8_t, b), c, 0, 0, 0);
}
static __device__ __forceinline__ float sigmoidf_(float x) { return 1.f / (1.f + __expf(-x)); }
static __device__ __forceinline__ float tanhf_(float x) { return 1.f - 2.f / (__expf(2.f * x) + 1.f); }

// true iff none of the four u16 lanes equals the sentinel 0x7FFF
static __device__ __forceinline__ bool no_sent(u64 v) {
  u64 x = v ^ 0x7FFF7FFF7FFF7FFFull;  // sentinel lane -> 0x0000
  return (((x - 0x0001000100010001ull) & ~x & 0x8000800080008000ull) == 0);
}
static __device__ __forceinline__ bool ok16(u32x4_t v) {
  u64 a = ((u64)v[1] << 32) | v[0];
  u64 b = ((u64)v[3] << 32) | v[2];
  return no_sent(a) && no_sent(b);
}

// blocking 16B LLC-coherent load (bypasses L1 and L2) -- v13-proven path
static __device__ __forceinline__ u32x4_t llc_load16(const u32x4_t* p) {
  u32x4_t r;
  asm volatile("global_load_dwordx4 %0, %1, off sc0 sc1\n\t"
               "s_waitcnt vmcnt(0)"
               : "=&v"(r) : "v"(p) : "memory");
  return r;
}
// 2B LLC write-through store (lands at the coherence point)
static __device__ __forceinline__ void llc_store2(u16* p, unsigned v) {
  asm volatile("global_store_short %0, %1, off sc0 sc1" :: "v"(p), "v"(v) : "memory");
}

// ---- merged prep: poison x1 + wpack swizzle + MLP W^T, one launch ----------
// blocks [0,8192): poison x1 with f16-NaN sentinel 0x7FFF (h in [-1,1] can
//   never produce it; "!= sentinel" certifies this launch's store landed).
// blocks [8192,11264): wpack[dir][tau][kb][lane][8], tau=jb*4+g; element e:
//   n=g*256+jb*16+mrow, k=kb*32+quad*8+e; val = k<128?Wi[k][n]:Wh[k-128][n].
// blocks [11264,12160): w1t/w2t/w3t = W^T in f16.
__global__ __launch_bounds__(256) void prep_all(
    const float* __restrict__ Wi_f, const float* __restrict__ Wh_f,
    const float* __restrict__ Wi_r, const float* __restrict__ Wh_r,
    const float* __restrict__ W1, const float* __restrict__ W2,
    const float* __restrict__ W3, u16* __restrict__ wpack,
    u16* __restrict__ w1t, u16* __restrict__ w2t, u16* __restrict__ w3t,
    uint4* __restrict__ x1v) {
  int b = blockIdx.x;
  if (b < 8192) {  // poison: 32 B/thread -> 64 MB
    size_t id = (size_t)b * 256 + threadIdx.x;
    const uint4 s = {0x7FFF7FFFu, 0x7FFF7FFFu, 0x7FFF7FFFu, 0x7FFF7FFFu};
    x1v[id * 2] = s;
    x1v[id * 2 + 1] = s;
    return;
  }
  if (b < 11264) {  // wpack
    int id = (b - 8192) * 256 + threadIdx.x;
    if (id >= 786432) return;  // 2*64*12*64*8
    int e = id & 7, r = id >> 3;
    int lane = r & 63; r >>= 6;
    int kb = r % 12; r /= 12;
    int tau = r & 63, dir = r >> 6;
    int mrow = lane & 15, quad = lane >> 4;
    int jb = tau >> 2, g = tau & 3;
    int n = g * 256 + jb * 16 + mrow;
    int k = kb * 32 + quad * 8 + e;
    const float* Wi = dir ? Wi_r : Wi_f;
    const float* Wh = dir ? Wh_r : Wh_f;
    float v = (k < 128) ? Wi[k * 1024 + n] : Wh[(k - 128) * 1024 + n];
    wpack[id] = f2h(v);
    return;
  }
  int id = (b - 11264) * 256 + threadIdx.x;
  if (id < 131072) { int n = id >> 9, k = id & 511; w1t[id] = f2h(W1[k * 256 + n]); return; }
  id -= 131072;
  if (id < 65536) { int n = id >> 8, k = id & 255; w2t[id] = f2h(W2[k * 256 + n]); return; }
  id -= 65536;
  if (id < 32768) { int n = id >> 8, k = id & 255; w3t[id] = f2h(W3[k * 128 + n]); }
}

// ---- bidirectional LSTM v21: producer-consumer wave specialization ---------
// 256 blocks = q(4) x dir(2) x grp(32), 512 threads = 8 waves.
// Waves 0-3 (COMPUTE): v20's in-register all-4-gates structure -- wave w owns
//   jb=4q+w (taus 16q+4w+{0..3}); x-proj -> h-MFMA -> in-reg gates -> 2B
//   sc0|sc1 h-stores. Math/order identical to v20/v13 -> bit-identical.
// Waves 4-7 (STAGING): poll the 4 sibling blocks' h_t (sentinel 0x7FFF
//   protocol, LLC loads) for the ENTIRE step, concurrently with compute, and
//   write it swizzled into ah[(t+1)&1]. The store->detect window is thus
//   overlapped with compute instead of being serialized after it (v20's
//   regression showed the exposed poll, not the publish tail, is the cost).
// Buffer safety with ONE barrier/step: stage(t+1) writes ah[(t+1)&1], whose
// previous readers (compute, step t-1) passed barrier(t-1); compute(t) reads
// ah[t&1], staged during iteration t-1 and sealed by barrier(t-1).
__global__ __launch_bounds__(512, 1) void lstm_kernel(
    const float* __restrict__ x0, const u16* __restrict__ wpack,
    const float* __restrict__ bi_f, const float* __restrict__ bh_f,
    const float* __restrict__ bi_r, const float* __restrict__ bh_r,
    u16* __restrict__ x1) {
  __shared__ __align__(16) u16 lwh[16][8][64][8];  // 128 KB Wh kb4..11, 16 taus
  __shared__ __align__(16) u16 ah[2][16][256];     // 16 KB h panel, dbuf + swz

  const int tid = threadIdx.x;
  const int lane = tid & 63;
  const int w = tid >> 6;             // wave 0..7
  const int bid = blockIdx.x;
  const int q = bid >> 6;             // gate-slice 0..3
  const int rem = bid & 63;
  const int dir = rem >> 5;
  const int grp = rem & 31;
  const int b0 = grp * 16;
  const u16* wpk = wpack + (size_t)dir * (64 * 12 * 64 * 8);
  const float* bi = dir ? bi_r : bi_f;
  const float* bh = dir ? bh_r : bh_f;
  const int mrow = lane & 15, quad = lane >> 4;
  const bool is_compute = (w < 4);
  const int tauL0 = 4 * (w & 3);      // compute wave's first local tau

  // Wh kb4..11 for the block's 16 taus -> LDS (8192 frags, 16/thread)
#pragma unroll
  for (int r = 0; r < 16; ++r) {
    int d = r * 512 + tid;
    int ltau = d >> 9, lkb = (d >> 6) & 7, ll = d & 63;
    *(i16x8_t*)&lwh[ltau][lkb][ll][0] =
        *(const i16x8_t*)(wpk + (((size_t)(16 * q + ltau) * 12 + 4 + lkb) * 64 + ll) * 8);
  }
  // h_{-1} = 0 (both parities)
  for (int i = tid; i < 2 * 16 * 256; i += 512) ((u16*)ah)[i] = 0;

  // compute-wave state
  float bias4[4];
  i16x8_t wir[4][4];
  if (is_compute) {
#pragma unroll
    for (int g = 0; g < 4; ++g) {
      int n = g * 256 + (4 * q + (w & 3)) * 16 + mrow;
      bias4[g] = bi[n] + bh[n];
#pragma unroll
      for (int kb = 0; kb < 4; ++kb) {
        wir[g][kb] = *(const i16x8_t*)(wpk +
            (((size_t)(16 * q + tauL0 + g) * 12 + kb) * 64 + lane) * 8);
        PIN(wir[g][kb]);
      }
    }
  }
  __syncthreads();  // lwh + ah ready

  float c4[4] = {};
  const float* xfrag_base = x0 + (size_t)(b0 + mrow) * 16384 + quad * 8;
  u16* hstore_base =
      x1 + (size_t)(b0 + quad * 4) * 65536 + dir * 256 + 64 * q + (w & 3) * 16 + mrow;
  // staging-wave mapping: st in [0,256), 32 B/thread (2x16B polls)
  const int st = tid & 255;
  const int fm = st >> 4, fj = (st & 15) * 16;
  const int swz = (fm & 7) << 3;
  const u16* hstage_src = x1 + (size_t)(b0 + fm) * 65536 + dir * 256 + fj;

  for (int t = 0; t < 128; ++t) {
    if (is_compute) {
      const int teff = dir ? 127 - t : t;
      // x fragments + x-projection
      i16x8_t afx[4];
      {
        const float* xp = xfrag_base + (size_t)teff * 128;
#pragma unroll
        for (int kb = 0; kb < 4; ++kb) {
          float4 va = *(const float4*)(xp + kb * 32);
          float4 vb = *(const float4*)(xp + kb * 32 + 4);
          i16x8_t v;
          v[0] = (short)f2h(va.x); v[1] = (short)f2h(va.y);
          v[2] = (short)f2h(va.z); v[3] = (short)f2h(va.w);
          v[4] = (short)f2h(vb.x); v[5] = (short)f2h(vb.y);
          v[6] = (short)f2h(vb.z); v[7] = (short)f2h(vb.w);
          afx[kb] = v;
        }
      }
      f32x4_t acc[4];
#pragma unroll
      for (int g = 0; g < 4; ++g) {
        float bv = bias4[g];
        f32x4_t a = {bv, bv, bv, bv};
        a = mfma16h(afx[0], wir[g][0], a);
        a = mfma16h(afx[1], wir[g][1], a);
        a = mfma16h(afx[2], wir[g][2], a);
        a = mfma16h(afx[3], wir[g][3], a);
        acc[g] = a;
      }
      if (t > 0) {  // h-part MFMAs from ah[t&1] (staged during iter t-1)
        const int par = t & 1;
        i16x8_t afh[8];
#pragma unroll
        for (int kb = 0; kb < 8; ++kb)
          afh[kb] = *(const i16x8_t*)&ah[par][mrow][(kb * 32 + quad * 8) ^ ((mrow & 7) << 3)];
#pragma unroll
        for (int g = 0; g < 4; ++g) {
#pragma unroll
          for (int kb = 0; kb < 8; ++kb)
            acc[g] = mfma16h(afh[kb], *(const i16x8_t*)&lwh[tauL0 + g][kb][lane][0], acc[g]);
        }
      }
      // in-register gates; store h_t immediately (2B sc0|sc1)
#pragma unroll
      for (int r = 0; r < 4; ++r) {
        float fv = sigmoidf_(acc[0][r]);
        float iv = sigmoidf_(acc[1][r]);
        float av = tanhf_(acc[2][r]);
        float ov = sigmoidf_(acc[3][r]);
        float cv = fv * c4[r] + iv * av;
        c4[r] = cv;
        float hv = ov * tanhf_(cv);
        llc_store2(hstore_base + ((size_t)r * 128 + t) * 512, (unsigned)f2h(hv));
      }
    } else if (t < 127) {
      // STAGING: poll siblings' h_t (stored by compute waves this step),
      // write into ah[(t+1)&1]. Overlaps the entire compute phase.
      const u32x4_t* hsrc = (const u32x4_t*)(hstage_src + (size_t)t * 512);
      u32x4_t h0 = llc_load16(hsrc);
      u32x4_t h1 = llc_load16(hsrc + 1);
      unsigned iter = 0;
      while (!(ok16(h0) && ok16(h1))) {
        __builtin_amdgcn_s_sleep(1);
        if (!ok16(h0)) h0 = llc_load16(hsrc);
        if (!ok16(h1)) h1 = llc_load16(hsrc + 1);
        if (++iter > (1u << 20)) break;  // fail-safe: bug -> wrong, not hang
      }
      u16* abase = &ah[(t + 1) & 1][0][0];
      *(u32x4_t*)(abase + fm * 256 + (fj ^ swz)) = h0;
      *(u32x4_t*)(abase + fm * 256 + ((fj + 8) ^ swz)) = h1;
    }
    __syncthreads();  // seals stage(t+1) and compute(t); one barrier/step
  }
}

// ---- fused MLP + heads v19: N-partitioned waves + LDS-staged A (unchanged) -
__global__ __launch_bounds__(512, 1) void mlp_kernel(
    const u16* __restrict__ x1, const u16* __restrict__ w1t,
    const u16* __restrict__ w2t, const u16* __restrict__ w3t,
    const float* __restrict__ b1, const float* __restrict__ b2,
    const float* __restrict__ b3, float* __restrict__ out) {
  __shared__ __align__(16) u16 xa[64][520];   // 66.6 KB staged x1 tile
  __shared__ __align__(16) u16 X2[64][264];   // 33.8 KB
  __shared__ __align__(16) u16 X3[64][264];   // 33.8 KB
  const int tid = threadIdx.x;
  const int lane = tid & 63;
  const int wv = tid >> 6;                 // wave 0..7 = N-group
  const int mrow = lane & 15, quad = lane >> 4;
  const int r0 = blockIdx.x * 64;
  const f32x4_t zero4 = {0.f, 0.f, 0.f, 0.f};

  // stage x1 tile -> LDS (coalesced 16B chunks)
#pragma unroll
  for (int i = 0; i < 8; ++i) {
    int idx = i * 512 + tid;               // 4096 chunks of 16 B
    int row = idx >> 6, ch = idx & 63;
    *(i16x8_t*)&xa[row][ch * 8] =
        *(const i16x8_t*)(x1 + (size_t)(r0 + row) * 512 + ch * 8);
  }
  __syncthreads();

  // stage 1: X2[64][256] = leaky(xa @ W1 + b1); wave owns n-tiles {2wv,2wv+1}
  {
    f32x4_t acc[2][4];
#pragma unroll
    for (int n = 0; n < 2; ++n)
#pragma unroll
      for (int rg = 0; rg < 4; ++rg) acc[n][rg] = zero4;
    for (int kb = 0; kb < 16; ++kb) {
      int k = kb * 32 + quad * 8;
      i16x8_t bf0 = *(const i16x8_t*)(w1t + ((wv * 2 + 0) * 16 + mrow) * 512 + k);
      i16x8_t bf1 = *(const i16x8_t*)(w1t + ((wv * 2 + 1) * 16 + mrow) * 512 + k);
#pragma unroll
      for (int rg = 0; rg < 4; ++rg) {
        i16x8_t a = *(const i16x8_t*)&xa[rg * 16 + mrow][k];
        acc[0][rg] = mfma16h(a, bf0, acc[0][rg]);
        acc[1][rg] = mfma16h(a, bf1, acc[1][rg]);
      }
    }
#pragma unroll
    for (int n = 0; n < 2; ++n)
#pragma unroll
      for (int rg = 0; rg < 4; ++rg)
#pragma unroll
        for (int r = 0; r < 4; ++r) {
          int m = rg * 16 + quad * 4 + r;
          int col = (wv * 2 + n) * 16 + mrow;
          float v = acc[n][rg][r] + b1[col];
          v = v > 0.f ? v : 0.1f * v;
          X2[m][col] = f2h(v);
        }
  }
  __syncthreads();

  // stage 2: X3[64][256] = leaky(X2 @ W2 + b2), K=256
  {
    f32x4_t acc[2][4];
#pragma unroll
    for (int n = 0; n < 2; ++n)
#pragma unroll
      for (int rg = 0; rg < 4; ++rg) acc[n][rg] = zero4;
#pragma unroll
    for (int kb = 0; kb < 8; ++kb) {
      int k = kb * 32 + quad * 8;
      i16x8_t bf0 = *(const i16x8_t*)(w2t + ((wv * 2 + 0) * 16 + mrow) * 256 + k);
      i16x8_t bf1 = *(const i16x8_t*)(w2t + ((wv * 2 + 1) * 16 + mrow) * 256 + k);
#pragma unroll
      for (int rg = 0; rg < 4; ++rg) {
        i16x8_t a = *(const i16x8_t*)&X2[rg * 16 + mrow][k];
        acc[0][rg] = mfma16h(a, bf0, acc[0][rg]);
        acc[1][rg] = mfma16h(a, bf1, acc[1][rg]);
      }
    }
#pragma unroll
    for (int n = 0; n < 2; ++n)
#pragma unroll
      for (int rg = 0; rg < 4; ++rg)
#pragma unroll
        for (int r = 0; r < 4; ++r) {
          int m = rg * 16 + quad * 4 + r;
          int col = (wv * 2 + n) * 16 + mrow;
          float v = acc[n][rg][r] + b2[col];
          v = v > 0.f ? v : 0.1f * v;
          X3[m][col] = f2h(v);
        }
  }
  __syncthreads();

  // stage 3: XF[64][128] = X3 @ W3 + b3 (fp32; overlays dead X2)
  float (*XF)[130] = (float (*)[130]) & X2[0][0];  // 64*130*4 = 33.3 KB <= X2
  {
    f32x4_t acc[4];
#pragma unroll
    for (int rg = 0; rg < 4; ++rg) acc[rg] = zero4;
#pragma unroll
    for (int kb = 0; kb < 8; ++kb) {
      int k = kb * 32 + quad * 8;
      i16x8_t bf = *(const i16x8_t*)(w3t + (wv * 16 + mrow) * 256 + k);
#pragma unroll
      for (int rg = 0; rg < 4; ++rg) {
        i16x8_t a = *(const i16x8_t*)&X3[rg * 16 + mrow][k];
        acc[rg] = mfma16h(a, bf, acc[rg]);
      }
    }
#pragma unroll
    for (int rg = 0; rg < 4; ++rg)
#pragma unroll
      for (int r = 0; r < 4; ++r) {
        int m = rg * 16 + quad * 4 + r;
        int col = wv * 16 + mrow;
        XF[m][col] = acc[rg][r] + b3[col];
      }
  }
  __syncthreads();

  // heads (parallel, 512 threads): sigmoid 4096 elems -> 8/thread;
  // softmax: 192 (row,seg) tasks -> one per thread (tid<192).
  for (int i = 0; i < 8; ++i) {
    int idx = tid * 8 + i;              // 4096 = 64 rows x 64 cols
    int row = idx >> 6, cc = idx & 63;
    out[(size_t)(r0 + row) * 128 + cc] = sigmoidf_(XF[row][cc]);
  }
  if (tid < 192) {
    int row = tid / 3;
    int s = tid % 3;
    const int s0s[3] = {64, 72, 88};
    const int s1s[3] = {72, 88, 128};
    int s0 = s0s[s], s1 = s1s[s];
    float* xr = XF[row];
    float* op = out + (size_t)(r0 + row) * 128;
    float mx = xr[s0];
    for (int qq = s0 + 1; qq < s1; ++qq) mx = fmaxf(mx, xr[qq]);
    float sum = 0.f;
    for (int qq = s0; qq < s1; ++qq) { float e = __expf(xr[qq] - mx); xr[qq] = e; sum += e; }
    float inv = 1.f / sum;
    for (int qq = s0; qq < s1; ++qq) op[qq] = xr[qq] * inv;
  }
}

// ---- launch ----------------------------------------------------------------
extern "C" void kernel_launch(void* const* d_in, const int* in_sizes, int n_in,
                              void* d_out, int out_size, void* d_ws, size_t ws_size,
                              hipStream_t stream) {
  const float* x0   = (const float*)d_in[0];
  const float* Wi_f = (const float*)d_in[1];
  const float* bi_f = (const float*)d_in[2];
  const float* Wh_f = (const float*)d_in[3];
  const float* bh_f = (const float*)d_in[4];
  const float* Wi_r = (const float*)d_in[5];
  const float* bi_r = (const float*)d_in[6];
  const float* Wh_r = (const float*)d_in[7];
  const float* bh_r = (const float*)d_in[8];
  const float* W1 = (const float*)d_in[9];
  const float* b1 = (const float*)d_in[10];
  const float* W2 = (const float*)d_in[11];
  const float* b2 = (const float*)d_in[12];
  const float* W3 = (const float*)d_in[13];
  const float* b3 = (const float*)d_in[14];
  float* out = (float*)d_out;

  char* ws = (char*)d_ws;
  u16* w1t   = (u16*)(ws + 0);         // 262144 B
  u16* w2t   = (u16*)(ws + 262144);    // 131072 B
  u16* w3t   = (u16*)(ws + 393216);    // 65536 B
  u16* wpack = (u16*)(ws + 458752);    // 1572864 B
  u16* x1    = (u16*)(ws + 2031616);   // 67108864 B

  hipLaunchKernelGGL(prep_all, dim3(12160), dim3(256), 0, stream,
                     Wi_f, Wh_f, Wi_r, Wh_r, W1, W2, W3,
                     wpack, w1t, w2t, w3t, (uint4*)x1);
  hipLaunchKernelGGL(lstm_kernel, dim3(256), dim3(512), 0, stream,
                     x0, wpack, bi_f, bh_f, bi_r, bh_r, x1);
  hipLaunchKernelGGL(mlp_kernel, dim3(1024), dim3(512), 0, stream,
                     x1, w1t, w2t, w3t, b1, b2, b3, out);
}

// Round 21
// 537.585 us; speedup vs baseline: 1.5075x; 1.5075x over previous
//
#include <hip/hip_runtime.h>

typedef unsigned short u16;
typedef unsigned long long u64;
typedef unsigned u32x4_t __attribute__((ext_vector_type(4)));
typedef _Float16 f16x8_t __attribute__((ext_vector_type(8)));
typedef short    i16x8_t __attribute__((ext_vector_type(8)));
typedef float    f32x4_t __attribute__((ext_vector_type(4)));

// force a loaded value to stay materialized in VGPRs (no remat/sinking)
#define PIN(x) asm volatile("" : "+v"(x))

// ---- helpers ---------------------------------------------------------------
static __device__ __forceinline__ u16 f2h(float f) {
  _Float16 h = (_Float16)f;  // RNE
  return __builtin_bit_cast(u16, h);
}
static __device__ __forceinline__ f32x4_t mfma16h(i16x8_t a, i16x8_t b, f32x4_t c) {
  return __builtin_amdgcn_mfma_f32_16x16x32_f16(
      __builtin_bit_cast(f16x8_t, a), __builtin_bit_cast(f16x8_t, b), c, 0, 0, 0);
}
static __device__ __forceinline__ float sigmoidf_(float x) { return 1.f / (1.f + __expf(-x)); }
static __device__ __forceinline__ float tanhf_(float x) { return 1.f - 2.f / (__expf(2.f * x) + 1.f); }

// true iff none of the four u16 lanes equals the sentinel 0x7FFF
static __device__ __forceinline__ bool no_sent(u64 v) {
  u64 x = v ^ 0x7FFF7FFF7FFF7FFFull;  // sentinel lane -> 0x0000
  return (((x - 0x0001000100010001ull) & ~x & 0x8000800080008000ull) == 0);
}
static __device__ __forceinline__ bool ok16(u32x4_t v) {
  u64 a = ((u64)v[1] << 32) | v[0];
  u64 b = ((u64)v[3] << 32) | v[2];
  return no_sent(a) && no_sent(b);
}

// blocking 16B LLC-coherent load (bypasses L1 and L2) -- v13-proven path
static __device__ __forceinline__ u32x4_t llc_load16(const u32x4_t* p) {
  u32x4_t r;
  asm volatile("global_load_dwordx4 %0, %1, off sc0 sc1\n\t"
               "s_waitcnt vmcnt(0)"
               : "=&v"(r) : "v"(p) : "memory");
  return r;
}
// 2B LLC write-through store (lands at the coherence point)
static __device__ __forceinline__ void llc_store2(u16* p, unsigned v) {
  asm volatile("global_store_short %0, %1, off sc0 sc1" :: "v"(p), "v"(v) : "memory");
}

// ---- merged prep: poison x1 + wpack swizzle + MLP W^T, one launch ----------
// blocks [0,8192): poison x1 with f16-NaN sentinel 0x7FFF (h in [-1,1] can
//   never produce it; "!= sentinel" certifies this launch's store landed).
// blocks [8192,11264): wpack[dir][tau][kb][lane][8], tau=jb*4+g; element e:
//   n=g*256+jb*16+mrow, k=kb*32+quad*8+e; val = k<128?Wi[k][n]:Wh[k-128][n].
// blocks [11264,12160): w1t/w2t/w3t = W^T in f16.
__global__ __launch_bounds__(256) void prep_all(
    const float* __restrict__ Wi_f, const float* __restrict__ Wh_f,
    const float* __restrict__ Wi_r, const float* __restrict__ Wh_r,
    const float* __restrict__ W1, const float* __restrict__ W2,
    const float* __restrict__ W3, u16* __restrict__ wpack,
    u16* __restrict__ w1t, u16* __restrict__ w2t, u16* __restrict__ w3t,
    uint4* __restrict__ x1v) {
  int b = blockIdx.x;
  if (b < 8192) {  // poison: 32 B/thread -> 64 MB
    size_t id = (size_t)b * 256 + threadIdx.x;
    const uint4 s = {0x7FFF7FFFu, 0x7FFF7FFFu, 0x7FFF7FFFu, 0x7FFF7FFFu};
    x1v[id * 2] = s;
    x1v[id * 2 + 1] = s;
    return;
  }
  if (b < 11264) {  // wpack
    int id = (b - 8192) * 256 + threadIdx.x;
    if (id >= 786432) return;  // 2*64*12*64*8
    int e = id & 7, r = id >> 3;
    int lane = r & 63; r >>= 6;
    int kb = r % 12; r /= 12;
    int tau = r & 63, dir = r >> 6;
    int mrow = lane & 15, quad = lane >> 4;
    int jb = tau >> 2, g = tau & 3;
    int n = g * 256 + jb * 16 + mrow;
    int k = kb * 32 + quad * 8 + e;
    const float* Wi = dir ? Wi_r : Wi_f;
    const float* Wh = dir ? Wh_r : Wh_f;
    float v = (k < 128) ? Wi[k * 1024 + n] : Wh[(k - 128) * 1024 + n];
    wpack[id] = f2h(v);
    return;
  }
  int id = (b - 11264) * 256 + threadIdx.x;
  if (id < 131072) { int n = id >> 9, k = id & 511; w1t[id] = f2h(W1[k * 256 + n]); return; }
  id -= 131072;
  if (id < 65536) { int n = id >> 8, k = id & 255; w2t[id] = f2h(W2[k * 256 + n]); return; }
  id -= 65536;
  if (id < 32768) { int n = id >> 8, k = id & 255; w3t[id] = f2h(W3[k * 128 + n]); }
}

// ---- bidirectional LSTM v20: all-4-gates-per-wave, in-register gate phase --
// 256 blocks = q(4 gate-slices) x dir(2) x grp(32 batch-groups of 16 rows),
// but now 256 threads = 4 waves; wave w owns jb = 4q+w -> taus 16q+4w+{0..3}
// (ALL FOUR GATES of one 16x16 cell tile). MFMA C-layout puts f/i/a/o for
// cell (quad*4+r, mrow) in the same lane at the same r across the 4 accs ->
// gate nonlinearity + c-state run fully in registers; the gbuf LDS round-trip
// and barrier B of v13 are DELETED. ah is double-buffered (stage(t) writes
// ah[t&1]; readers of it last touched it at t-2, separated by barrier(t-1)
// -> one barrier/step is sufficient). Exchange protocol (sentinel 0x7FFF,
// sc0|sc1 LLC loads/stores) is v13-verbatim; accumulation order per
// (cell,tau) unchanged (bias -> Wi kb0..3 -> Wh kb0..7) -> bit-identical.
// Known floor: one LLC store->detect visibility hop per step (bracketed
// 478-495us across v12/v13/v16/v17/v20; overlap attempts v14/v16/v21 all
// null or regressed -- the recurrence has no independent work to hide it).
__global__ __launch_bounds__(256, 1) void lstm_kernel(
    const float* __restrict__ x0, const u16* __restrict__ wpack,
    const float* __restrict__ bi_f, const float* __restrict__ bh_f,
    const float* __restrict__ bi_r, const float* __restrict__ bh_r,
    u16* __restrict__ x1) {
  __shared__ __align__(16) u16 lwh[16][8][64][8];  // 128 KB Wh kb4..11, 16 taus
  __shared__ __align__(16) u16 ah[2][16][256];     // 16 KB h panel, dbuf + swz

  const int tid = threadIdx.x;
  const int lane = tid & 63;
  const int w = tid >> 6;             // wave 0..3 (owns jb = 4q+w)
  const int bid = blockIdx.x;
  const int q = bid >> 6;             // gate-slice 0..3
  const int rem = bid & 63;
  const int dir = rem >> 5;
  const int grp = rem & 31;
  const int b0 = grp * 16;
  const u16* wpk = wpack + (size_t)dir * (64 * 12 * 64 * 8);
  const float* bi = dir ? bi_r : bi_f;
  const float* bh = dir ? bh_r : bh_f;
  const int mrow = lane & 15, quad = lane >> 4;
  const int tauL0 = 4 * w;            // wave's first local tau (of 16)

  // biases for the wave's 4 gates (same jb = 4q+w)
  float bias4[4];
#pragma unroll
  for (int g = 0; g < 4; ++g) {
    int n = g * 256 + (4 * q + w) * 16 + mrow;
    bias4[g] = bi[n] + bh[n];
  }

  // Wh kb4..11 for the block's 16 taus -> LDS (8192 frags of 16 B, 32/thread)
#pragma unroll
  for (int r = 0; r < 32; ++r) {
    int d = r * 256 + tid;
    int ltau = d >> 9, lkb = (d >> 6) & 7, ll = d & 63;
    *(i16x8_t*)&lwh[ltau][lkb][ll][0] =
        *(const i16x8_t*)(wpk + (((size_t)(16 * q + ltau) * 12 + 4 + lkb) * 64 + ll) * 8);
  }
  // Wi kb0..3 for the wave's 4 taus -> registers (64 VGPR), pinned
  i16x8_t wir[4][4];
#pragma unroll
  for (int g = 0; g < 4; ++g)
#pragma unroll
    for (int kb = 0; kb < 4; ++kb) {
      wir[g][kb] =
          *(const i16x8_t*)(wpk + (((size_t)(16 * q + tauL0 + g) * 12 + kb) * 64 + lane) * 8);
      PIN(wir[g][kb]);
    }
  // h_{-1} = 0 (both parities)
  for (int i = tid; i < 2 * 16 * 256; i += 256) ((u16*)ah)[i] = 0;
  __syncthreads();  // lwh + ah ready

  // c-state: lane owns 4 cells (row = quad*4+r, col = 64q + w*16 + mrow)
  float c4[4] = {};

  // per-lane global base for x-fragment loads (direct, pre-stage)
  const float* xfrag_base = x0 + (size_t)(b0 + mrow) * 16384 + quad * 8;
  // h staging: 32B/thread (2x16B polls), coalesced rows; LDS dst XOR-swizzled
  const int fm = tid >> 4, fj = (tid & 15) * 16;
  const int swz = (fm & 7) << 3;
  const u16* hstage_src = x1 + (size_t)(b0 + fm) * 65536 + dir * 256 + fj;
  // per-lane h-store base: row quad*4, col 64q + w*16 + mrow at time t
  u16* hstore_base = x1 + (size_t)(b0 + quad * 4) * 65536 + dir * 256 + 64 * q + w * 16 + mrow;

  for (int t = 0; t < 128; ++t) {
    const int teff = dir ? 127 - t : t;
    const int par = t & 1;

    // x fragments: direct from x0 (read-only, normal cached loads)
    i16x8_t afx[4];
    {
      const float* xp = xfrag_base + (size_t)teff * 128;
#pragma unroll
      for (int kb = 0; kb < 4; ++kb) {
        float4 va = *(const float4*)(xp + kb * 32);
        float4 vb = *(const float4*)(xp + kb * 32 + 4);
        i16x8_t v;
        v[0] = (short)f2h(va.x); v[1] = (short)f2h(va.y);
        v[2] = (short)f2h(va.z); v[3] = (short)f2h(va.w);
        v[4] = (short)f2h(vb.x); v[5] = (short)f2h(vb.y);
        v[6] = (short)f2h(vb.z); v[7] = (short)f2h(vb.w);
        afx[kb] = v;
      }
    }
    // x-projection MFMAs BEFORE staging (overlap with producers finishing)
    f32x4_t acc[4];
#pragma unroll
    for (int g = 0; g < 4; ++g) {
      float bv = bias4[g];
      f32x4_t a = {bv, bv, bv, bv};
      a = mfma16h(afx[0], wir[g][0], a);
      a = mfma16h(afx[1], wir[g][1], a);
      a = mfma16h(afx[2], wir[g][2], a);
      a = mfma16h(afx[3], wir[g][3], a);
      acc[g] = a;
    }

    // stage h_{t-1} into ah[par]: two 16B LLC polls/thread, retry on sentinel.
    // ah[par] overwrite is safe: its readers ran at t-2, and barrier(t-1)
    // separates them from this write on every thread.
    if (t > 0) {
      const u32x4_t* hsrc = (const u32x4_t*)(hstage_src + (size_t)(t - 1) * 512);
      u32x4_t h0 = llc_load16(hsrc);
      u32x4_t h1 = llc_load16(hsrc + 1);
      unsigned iter = 0;
      while (!(ok16(h0) && ok16(h1))) {
        __builtin_amdgcn_s_sleep(1);
        if (!ok16(h0)) h0 = llc_load16(hsrc);
        if (!ok16(h1)) h1 = llc_load16(hsrc + 1);
        if (++iter > (1u << 20)) break;  // fail-safe: bug -> wrong, not hang
      }
      u16* abase = &ah[par][0][0];
      *(u32x4_t*)(abase + fm * 256 + (fj ^ swz)) = h0;
      *(u32x4_t*)(abase + fm * 256 + ((fj + 8) ^ swz)) = h1;
    }
    __syncthreads();  // (A) ah[par] ready -- the ONLY barrier per step

    if (t > 0) {  // h-part MFMAs: conflict-free swizzled ds_read_b128
      i16x8_t afh[8];
#pragma unroll
      for (int kb = 0; kb < 8; ++kb)
        afh[kb] = *(const i16x8_t*)&ah[par][mrow][(kb * 32 + quad * 8) ^ ((mrow & 7) << 3)];
#pragma unroll
      for (int g = 0; g < 4; ++g) {
#pragma unroll
        for (int kb = 0; kb < 8; ++kb)
          acc[g] = mfma16h(afh[kb], *(const i16x8_t*)&lwh[tauL0 + g][kb][lane][0], acc[g]);
      }
    }

    // gate phase: fully in-register (f/i/a/o of cell (quad*4+r, mrow) are
    // acc[0..3][r] in this lane); store h immediately (2B sc0|sc1 stores,
    // 16-lane-contiguous 32B segments per quad-row).
#pragma unroll
    for (int r = 0; r < 4; ++r) {
      float fv = sigmoidf_(acc[0][r]);
      float iv = sigmoidf_(acc[1][r]);
      float av = tanhf_(acc[2][r]);
      float ov = sigmoidf_(acc[3][r]);
      float cv = fv * c4[r] + iv * av;
      c4[r] = cv;
      float hv = ov * tanhf_(cv);
      llc_store2(hstore_base + ((size_t)r * 128 + t) * 512, (unsigned)f2h(hv));
    }
    // no trailing barrier, no flag: the store IS the signal
  }
}

// ---- fused MLP + heads v19: N-partitioned waves + LDS-staged A (unchanged) -
// 8 waves partition N (wave owns 2 n-tiles stage1/2, 1 n-tile stage3, across
// all 64 rows) -> every B fragment loaded once per block; A tile staged once
// into LDS. Per-block global traffic 512 KB. Bit-identical math.
__global__ __launch_bounds__(512, 1) void mlp_kernel(
    const u16* __restrict__ x1, const u16* __restrict__ w1t,
    const u16* __restrict__ w2t, const u16* __restrict__ w3t,
    const float* __restrict__ b1, const float* __restrict__ b2,
    const float* __restrict__ b3, float* __restrict__ out) {
  __shared__ __align__(16) u16 xa[64][520];   // 66.6 KB staged x1 tile
  __shared__ __align__(16) u16 X2[64][264];   // 33.8 KB
  __shared__ __align__(16) u16 X3[64][264];   // 33.8 KB
  const int tid = threadIdx.x;
  const int lane = tid & 63;
  const int wv = tid >> 6;                 // wave 0..7 = N-group
  const int mrow = lane & 15, quad = lane >> 4;
  const int r0 = blockIdx.x * 64;
  const f32x4_t zero4 = {0.f, 0.f, 0.f, 0.f};

  // stage x1 tile -> LDS (coalesced 16B chunks)
#pragma unroll
  for (int i = 0; i < 8; ++i) {
    int idx = i * 512 + tid;               // 4096 chunks of 16 B
    int row = idx >> 6, ch = idx & 63;
    *(i16x8_t*)&xa[row][ch * 8] =
        *(const i16x8_t*)(x1 + (size_t)(r0 + row) * 512 + ch * 8);
  }
  __syncthreads();

  // stage 1: X2[64][256] = leaky(xa @ W1 + b1); wave owns n-tiles {2wv,2wv+1}
  {
    f32x4_t acc[2][4];
#pragma unroll
    for (int n = 0; n < 2; ++n)
#pragma unroll
      for (int rg = 0; rg < 4; ++rg) acc[n][rg] = zero4;
    for (int kb = 0; kb < 16; ++kb) {
      int k = kb * 32 + quad * 8;
      i16x8_t bf0 = *(const i16x8_t*)(w1t + ((wv * 2 + 0) * 16 + mrow) * 512 + k);
      i16x8_t bf1 = *(const i16x8_t*)(w1t + ((wv * 2 + 1) * 16 + mrow) * 512 + k);
#pragma unroll
      for (int rg = 0; rg < 4; ++rg) {
        i16x8_t a = *(const i16x8_t*)&xa[rg * 16 + mrow][k];
        acc[0][rg] = mfma16h(a, bf0, acc[0][rg]);
        acc[1][rg] = mfma16h(a, bf1, acc[1][rg]);
      }
    }
#pragma unroll
    for (int n = 0; n < 2; ++n)
#pragma unroll
      for (int rg = 0; rg < 4; ++rg)
#pragma unroll
        for (int r = 0; r < 4; ++r) {
          int m = rg * 16 + quad * 4 + r;
          int col = (wv * 2 + n) * 16 + mrow;
          float v = acc[n][rg][r] + b1[col];
          v = v > 0.f ? v : 0.1f * v;
          X2[m][col] = f2h(v);
        }
  }
  __syncthreads();

  // stage 2: X3[64][256] = leaky(X2 @ W2 + b2), K=256
  {
    f32x4_t acc[2][4];
#pragma unroll
    for (int n = 0; n < 2; ++n)
#pragma unroll
      for (int rg = 0; rg < 4; ++rg) acc[n][rg] = zero4;
#pragma unroll
    for (int kb = 0; kb < 8; ++kb) {
      int k = kb * 32 + quad * 8;
      i16x8_t bf0 = *(const i16x8_t*)(w2t + ((wv * 2 + 0) * 16 + mrow) * 256 + k);
      i16x8_t bf1 = *(const i16x8_t*)(w2t + ((wv * 2 + 1) * 16 + mrow) * 256 + k);
#pragma unroll
      for (int rg = 0; rg < 4; ++rg) {
        i16x8_t a = *(const i16x8_t*)&X2[rg * 16 + mrow][k];
        acc[0][rg] = mfma16h(a, bf0, acc[0][rg]);
        acc[1][rg] = mfma16h(a, bf1, acc[1][rg]);
      }
    }
#pragma unroll
    for (int n = 0; n < 2; ++n)
#pragma unroll
      for (int rg = 0; rg < 4; ++rg)
#pragma unroll
        for (int r = 0; r < 4; ++r) {
          int m = rg * 16 + quad * 4 + r;
          int col = (wv * 2 + n) * 16 + mrow;
          float v = acc[n][rg][r] + b2[col];
          v = v > 0.f ? v : 0.1f * v;
          X3[m][col] = f2h(v);
        }
  }
  __syncthreads();

  // stage 3: XF[64][128] = X3 @ W3 + b3 (fp32; overlays dead X2)
  float (*XF)[130] = (float (*)[130]) & X2[0][0];  // 64*130*4 = 33.3 KB <= X2
  {
    f32x4_t acc[4];
#pragma unroll
    for (int rg = 0; rg < 4; ++rg) acc[rg] = zero4;
#pragma unroll
    for (int kb = 0; kb < 8; ++kb) {
      int k = kb * 32 + quad * 8;
      i16x8_t bf = *(const i16x8_t*)(w3t + (wv * 16 + mrow) * 256 + k);
#pragma unroll
      for (int rg = 0; rg < 4; ++rg) {
        i16x8_t a = *(const i16x8_t*)&X3[rg * 16 + mrow][k];
        acc[rg] = mfma16h(a, bf, acc[rg]);
      }
    }
#pragma unroll
    for (int rg = 0; rg < 4; ++rg)
#pragma unroll
      for (int r = 0; r < 4; ++r) {
        int m = rg * 16 + quad * 4 + r;
        int col = wv * 16 + mrow;
        XF[m][col] = acc[rg][r] + b3[col];
      }
  }
  __syncthreads();

  // heads (parallel, 512 threads): sigmoid 4096 elems -> 8/thread;
  // softmax: 192 (row,seg) tasks -> one per thread (tid<192).
  for (int i = 0; i < 8; ++i) {
    int idx = tid * 8 + i;              // 4096 = 64 rows x 64 cols
    int row = idx >> 6, cc = idx & 63;
    out[(size_t)(r0 + row) * 128 + cc] = sigmoidf_(XF[row][cc]);
  }
  if (tid < 192) {
    int row = tid / 3;
    int s = tid % 3;
    const int s0s[3] = {64, 72, 88};
    const int s1s[3] = {72, 88, 128};
    int s0 = s0s[s], s1 = s1s[s];
    float* xr = XF[row];
    float* op = out + (size_t)(r0 + row) * 128;
    float mx = xr[s0];
    for (int qq = s0 + 1; qq < s1; ++qq) mx = fmaxf(mx, xr[qq]);
    float sum = 0.f;
    for (int qq = s0; qq < s1; ++qq) { float e = __expf(xr[qq] - mx); xr[qq] = e; sum += e; }
    float inv = 1.f / sum;
    for (int qq = s0; qq < s1; ++qq) op[qq] = xr[qq] * inv;
  }
}

// ---- launch ----------------------------------------------------------------
extern "C" void kernel_launch(void* const* d_in, const int* in_sizes, int n_in,
                              void* d_out, int out_size, void* d_ws, size_t ws_size,
                              hipStream_t stream) {
  const float* x0   = (const float*)d_in[0];
  const float* Wi_f = (const float*)d_in[1];
  const float* bi_f = (const float*)d_in[2];
  const float* Wh_f = (const float*)d_in[3];
  const float* bh_f = (const float*)d_in[4];
  const float* Wi_r = (const float*)d_in[5];
  const float* bi_r = (const float*)d_in[6];
  const float* Wh_r = (const float*)d_in[7];
  const float* bh_r = (const float*)d_in[8];
  const float* W1 = (const float*)d_in[9];
  const float* b1 = (const float*)d_in[10];
  const float* W2 = (const float*)d_in[11];
  const float* b2 = (const float*)d_in[12];
  const float* W3 = (const float*)d_in[13];
  const float* b3 = (const float*)d_in[14];
  float* out = (float*)d_out;

  char* ws = (char*)d_ws;
  u16* w1t   = (u16*)(ws + 0);         // 262144 B
  u16* w2t   = (u16*)(ws + 262144);    // 131072 B
  u16* w3t   = (u16*)(ws + 393216);    // 65536 B
  u16* wpack = (u16*)(ws + 458752);    // 1572864 B
  u16* x1    = (u16*)(ws + 2031616);   // 67108864 B

  hipLaunchKernelGGL(prep_all, dim3(12160), dim3(256), 0, stream,
                     Wi_f, Wh_f, Wi_r, Wh_r, W1, W2, W3,
                     wpack, w1t, w2t, w3t, (uint4*)x1);
  hipLaunchKernelGGL(lstm_kernel, dim3(256), dim3(256), 0, stream,
                     x0, wpack, bi_f, bh_f, bi_r, bh_r, x1);
  hipLaunchKernelGGL(mlp_kernel, dim3(1024), dim3(512), 0, stream,
                     x1, w1t, w2t, w3t, b1, b2, b3, out);
}